// Round 1
// baseline (945.593 us; speedup 1.0000x reference)
//
#include <hip/hip_runtime.h>

#define N_NODES 100000
#define N_PAIRS 1600000
#define EDGE_NUM 30000
#define D 64
#define NEG_SLOPE 0.2f
#define TN 16  // nodes staged per block in gemm

// ---------------------------------------------------------------------------
// Kernel 1: Y[t] = (X @ Ww[t]^T + Wb[t]) * scale
//   wave w (0..3) of each 256-thread block computes weight-type t=w.
//   t=0 -> d_out (X0, no degV scale); t=1..3 -> ws Y, scaled by degV[t-1][n].
//   Each lane keeps its W row (64 floats) in registers; X rows broadcast
//   from LDS (same-address -> conflict-free broadcast).
// ---------------------------------------------------------------------------
__global__ __launch_bounds__(256) void gemm_kernel(
    const float* __restrict__ X, const float* __restrict__ degV,
    const float* __restrict__ Ww, const float* __restrict__ Wb,
    float* __restrict__ out0, float* __restrict__ Y)
{
    __shared__ float xs[TN][D];
    const int wave = threadIdx.x >> 6;   // 0..3 = weight type
    const int lane = threadIdx.x & 63;   // output channel o

    float w[64];
    const float* wrow = Ww + (size_t)(wave * 64 + lane) * 64;
    #pragma unroll
    for (int i = 0; i < 64; i += 4) {
        float4 v = *(const float4*)(wrow + i);
        w[i] = v.x; w[i+1] = v.y; w[i+2] = v.z; w[i+3] = v.w;
    }
    const float b = Wb[wave * 64 + lane];

    for (int base = blockIdx.x * TN; base < N_NODES; base += gridDim.x * TN) {
        const int ntile = min(TN, N_NODES - base);
        __syncthreads();
        {   // stage TN x 64 floats: 256 threads x one float4 each
            int n = threadIdx.x >> 4;          // 16 float4 per row
            int c = (threadIdx.x & 15) << 2;
            if (n < ntile)
                *(float4*)&xs[n][c] = *(const float4*)&X[(size_t)(base + n) * D + c];
        }
        __syncthreads();
        for (int n = 0; n < ntile; ++n) {
            float acc = 0.f;
            #pragma unroll
            for (int i = 0; i < 64; ++i) acc = fmaf(xs[n][i], w[i], acc);
            acc += b;
            const int node = base + n;
            if (wave == 0) {
                out0[(size_t)node * D + lane] = acc;
            } else {
                const float s = degV[(size_t)(wave - 1) * N_NODES + node];
                Y[((size_t)(wave - 1) * N_NODES + node) * D + lane] = acc * s;
            }
        }
    }
}

// ---------------------------------------------------------------------------
// Kernel 2: pair -> edge scatter (fused type select).
//   One wave per pair: lane o atomically adds Y[etype(e)][v][o] into seg[e][o].
// ---------------------------------------------------------------------------
__global__ __launch_bounds__(256) void scatter_edge_kernel(
    const float* __restrict__ Y, const int* __restrict__ vertex,
    const int* __restrict__ edges, float* __restrict__ seg,
    float* __restrict__ cnt)
{
    const int p = (blockIdx.x * blockDim.x + threadIdx.x) >> 6;
    const int lane = threadIdx.x & 63;
    if (p >= N_PAIRS) return;
    const int v = vertex[p];
    const int e = edges[p];
    const int t = (e >= 10000) + (e >= 20000);
    const float val = Y[((size_t)t * N_NODES + v) * D + lane];
    atomicAdd(&seg[(size_t)e * D + lane], val);
    if (lane == 0) atomicAdd(&cnt[e], 1.0f);
}

// ---------------------------------------------------------------------------
// Kernel 3: seg /= max(cnt,1)  (in place -> becomes Xe)
// ---------------------------------------------------------------------------
__global__ __launch_bounds__(256) void edge_div_kernel(
    float* __restrict__ seg, const float* __restrict__ cnt)
{
    const int i = blockIdx.x * blockDim.x + threadIdx.x;
    if (i < EDGE_NUM * D) {
        const float c = cnt[i >> 6];
        seg[i] = seg[i] / fmaxf(c, 1.0f);
    }
}

// ---------------------------------------------------------------------------
// Kernel 4: edge -> vertex scatter. out was pre-filled with X0 by gemm_kernel.
// ---------------------------------------------------------------------------
__global__ __launch_bounds__(256) void scatter_vertex_kernel(
    const float* __restrict__ Xe, const int* __restrict__ vertex,
    const int* __restrict__ edges, float* __restrict__ out)
{
    const int p = (blockIdx.x * blockDim.x + threadIdx.x) >> 6;
    const int lane = threadIdx.x & 63;
    if (p >= N_PAIRS) return;
    const int v = vertex[p];
    const int e = edges[p];
    atomicAdd(&out[(size_t)v * D + lane], Xe[(size_t)e * D + lane]);
}

// ---------------------------------------------------------------------------
// Kernel 5: row L2-normalize (zero guard) + leaky_relu(0.2), in place.
// ---------------------------------------------------------------------------
__global__ __launch_bounds__(256) void norm_leaky_kernel(float* __restrict__ out)
{
    const int n = (blockIdx.x * blockDim.x + threadIdx.x) >> 6;
    const int lane = threadIdx.x & 63;
    if (n >= N_NODES) return;
    float v = out[(size_t)n * D + lane];
    float ss = v * v;
    #pragma unroll
    for (int off = 1; off < 64; off <<= 1) ss += __shfl_xor(ss, off);
    const float rn = sqrtf(ss);
    const float scale = (rn == 0.f) ? 0.f : 1.f / rn;
    float y = v * scale;
    out[(size_t)n * D + lane] = (y > 0.f) ? y : NEG_SLOPE * y;
}

// ---------------------------------------------------------------------------
extern "C" void kernel_launch(void* const* d_in, const int* in_sizes, int n_in,
                              void* d_out, int out_size, void* d_ws, size_t ws_size,
                              hipStream_t stream)
{
    const float* X     = (const float*)d_in[0];   // (100000, 64)
    const float* degV  = (const float*)d_in[1];   // (3, 100000, 1)
    const float* Ww    = (const float*)d_in[2];   // (4, 64, 64)
    const float* Wb    = (const float*)d_in[3];   // (4, 64)
    const int*   vertex = (const int*)d_in[4];    // (1600000,)
    const int*   edges  = (const int*)d_in[5];    // (1600000,)
    float* out = (float*)d_out;                   // (100000, 64)

    // workspace layout
    char* ws = (char*)d_ws;
    float* Y   = (float*)ws;                                   // 3*100000*64 f32 = 76.8 MB
    float* seg = (float*)(ws + (size_t)3 * N_NODES * D * 4);   // 30000*64 f32   = 7.68 MB
    float* cnt = seg + (size_t)EDGE_NUM * D;                   // 30000 f32
    const size_t seg_cnt_bytes = ((size_t)EDGE_NUM * D + EDGE_NUM) * 4;

    hipMemsetAsync(seg, 0, seg_cnt_bytes, stream);

    gemm_kernel<<<1024, 256, 0, stream>>>(X, degV, Ww, Wb, out, Y);

    {   // one wave per pair, 4 pairs per block
        const int blocks = (N_PAIRS + 3) / 4;
        scatter_edge_kernel<<<blocks, 256, 0, stream>>>(Y, vertex, edges, seg, cnt);
    }

    edge_div_kernel<<<(EDGE_NUM * D + 255) / 256, 256, 0, stream>>>(seg, cnt);

    {
        const int blocks = (N_PAIRS + 3) / 4;
        scatter_vertex_kernel<<<blocks, 256, 0, stream>>>(seg, vertex, edges, out);
    }

    norm_leaky_kernel<<<(N_NODES * 64 + 255) / 256, 256, 0, stream>>>(out);
}

// Round 2
// 897.947 us; speedup vs baseline: 1.0531x; 1.0531x over previous
//
#include <hip/hip_runtime.h>

#define N_NODES 100000
#define N_PAIRS 1600000
#define EDGE_NUM 30000
#define D 64
#define NEG_SLOPE 0.2f
#define TN 16  // nodes staged per block in x0 gemm

// ---------------------------------------------------------------------------
// Kernel 1: X0 = X @ Ww[0]^T + Wb[0]  -> d_out (vertex gather adds onto it)
// ---------------------------------------------------------------------------
__global__ __launch_bounds__(256) void x0_kernel(
    const float* __restrict__ X, const float* __restrict__ Ww,
    const float* __restrict__ Wb, float* __restrict__ out0)
{
    __shared__ float xs[TN][D];
    const int wave = threadIdx.x >> 6;
    const int lane = threadIdx.x & 63;

    float w[64];
    const float* wrow = Ww + (size_t)lane * 64;
    #pragma unroll
    for (int i = 0; i < 64; i += 4) {
        float4 v = *(const float4*)(wrow + i);
        w[i] = v.x; w[i+1] = v.y; w[i+2] = v.z; w[i+3] = v.w;
    }
    const float b = Wb[lane];

    for (int base = blockIdx.x * TN; base < N_NODES; base += gridDim.x * TN) {
        const int ntile = min(TN, N_NODES - base);
        __syncthreads();
        {
            int n = threadIdx.x >> 4;
            int c = (threadIdx.x & 15) << 2;
            if (n < ntile)
                *(float4*)&xs[n][c] = *(const float4*)&X[(size_t)(base + n) * D + c];
        }
        __syncthreads();
        #pragma unroll
        for (int q = 0; q < 4; ++q) {
            const int n = wave * 4 + q;
            if (n < ntile) {
                float acc = 0.f;
                #pragma unroll
                for (int i = 0; i < 64; ++i) acc = fmaf(xs[n][i], w[i], acc);
                out0[(size_t)(base + n) * D + lane] = acc + b;
            }
        }
    }
}

// ---------------------------------------------------------------------------
// CSR build: histogram -> exclusive scan -> fill
// ---------------------------------------------------------------------------
__global__ __launch_bounds__(256) void hist_kernel(
    const int* __restrict__ key, int* __restrict__ cnt, int n)
{
    const int i = blockIdx.x * blockDim.x + threadIdx.x;
    if (i < n) atomicAdd(&cnt[key[i]], 1);
}

// single-block scan: off[i] = exclusive prefix of cnt; cur[i] = same (cnt may alias cur)
__global__ __launch_bounds__(1024) void scan_kernel(
    const int* cnt, int* off, int* cur, int n)
{
    __shared__ int wsum[16];
    __shared__ int s_carry;
    if (threadIdx.x == 0) s_carry = 0;
    __syncthreads();
    const int lane = threadIdx.x & 63;
    const int wave = threadIdx.x >> 6;

    for (int base = 0; base < n; base += 4096) {
        const int i0 = base + threadIdx.x * 4;
        int x0 = 0, x1 = 0, x2 = 0, x3 = 0;
        if (i0 + 3 < n) {
            int4 v = *(const int4*)&cnt[i0];
            x0 = v.x; x1 = v.y; x2 = v.z; x3 = v.w;
        } else {
            if (i0     < n) x0 = cnt[i0];
            if (i0 + 1 < n) x1 = cnt[i0 + 1];
            if (i0 + 2 < n) x2 = cnt[i0 + 2];
            if (i0 + 3 < n) x3 = cnt[i0 + 3];
        }
        const int tsum = x0 + x1 + x2 + x3;
        // wave-inclusive scan of tsum (shuffle, no barriers)
        int sc = tsum;
        #pragma unroll
        for (int s = 1; s < 64; s <<= 1) {
            int y = __shfl_up(sc, s);
            if (lane >= s) sc += y;
        }
        if (lane == 63) wsum[wave] = sc;
        __syncthreads();
        int wbase = 0;
        for (int w = 0; w < wave; ++w) wbase += wsum[w];
        const int carry = s_carry;
        const int excl = carry + wbase + sc - tsum;
        const int o0 = excl, o1 = o0 + x0, o2 = o1 + x1, o3 = o2 + x2;
        if (i0 + 3 < n) {
            *(int4*)&off[i0] = make_int4(o0, o1, o2, o3);
            *(int4*)&cur[i0] = make_int4(o0, o1, o2, o3);
        } else {
            if (i0     < n) { off[i0]   = o0; cur[i0]   = o0; }
            if (i0 + 1 < n) { off[i0+1] = o1; cur[i0+1] = o1; }
            if (i0 + 2 < n) { off[i0+2] = o2; cur[i0+2] = o2; }
            if (i0 + 3 < n) { off[i0+3] = o3; cur[i0+3] = o3; }
        }
        __syncthreads();                 // everyone has read s_carry / wsum
        if (threadIdx.x == 1023) s_carry = carry + wbase + sc;
        __syncthreads();
    }
    if (threadIdx.x == 0) off[n] = s_carry;
}

__global__ __launch_bounds__(256) void fill_kernel(
    const int* __restrict__ key, const int* __restrict__ val,
    int* __restrict__ cur, int* __restrict__ list, int n)
{
    const int i = blockIdx.x * blockDim.x + threadIdx.x;
    if (i < n) {
        const int pos = atomicAdd(&cur[key[i]], 1);
        list[pos] = val[i];
    }
}

// ---------------------------------------------------------------------------
// Kernel: per-edge gather.
//   Xe[e] = ((sum_{v in e} degV[t][v]*X[v]) @ W[t+1]^T + (sum degV)*b[t+1]) / max(k,1)
//   One wave per edge; type t uniform per block (boundaries 10000/20000 are
//   multiples of 4). Lane o holds W[t+1][o][:] in 64 VGPRs.
// ---------------------------------------------------------------------------
__global__ __launch_bounds__(256) void edge_gather_kernel(
    const float* __restrict__ X, const float* __restrict__ degV,
    const float* __restrict__ Ww, const float* __restrict__ Wb,
    const int* __restrict__ eoff, const int* __restrict__ evlist,
    float* __restrict__ Xe)
{
    const int lane = threadIdx.x & 63;
    const int wave = threadIdx.x >> 6;
    const int e0 = blockIdx.x * 4;
    const int t = (e0 >= 10000) + (e0 >= 20000);   // uniform in block

    float w[64];
    const float* wrow = Ww + ((size_t)(t + 1) * 64 + lane) * 64;
    #pragma unroll
    for (int i = 0; i < 64; i += 4) {
        float4 v = *(const float4*)(wrow + i);
        w[i] = v.x; w[i+1] = v.y; w[i+2] = v.z; w[i+3] = v.w;
    }
    const float b = Wb[(t + 1) * 64 + lane];

    const int e = e0 + wave;
    if (e >= EDGE_NUM) return;
    const int start = eoff[e], end = eoff[e + 1];
    const float* degt = degV + (size_t)t * N_NODES;

    float acc = 0.f, sdeg = 0.f;
    for (int j0 = start; j0 < end; j0 += 64) {
        const int m = min(64, end - j0);
        const int vv = (lane < m) ? evlist[j0 + lane] : 0;
        for (int j = 0; j < m; ++j) {
            const int v = __shfl(vv, j);
            const float s = degt[v];
            acc = fmaf(s, X[(size_t)v * D + lane], acc);
            sdeg += s;
        }
    }
    // r[lane] = sum_i acc_i * W[lane][i]  via wave broadcast
    float r = 0.f;
    #pragma unroll
    for (int i = 0; i < 64; ++i) r = fmaf(__shfl(acc, i), w[i], r);
    r += sdeg * b;
    const int k = max(end - start, 1);
    Xe[(size_t)e * D + lane] = r / (float)k;
}

// ---------------------------------------------------------------------------
// Kernel: per-vertex gather + X0 add + L2 normalize + leaky relu (in place)
// ---------------------------------------------------------------------------
__global__ __launch_bounds__(256) void vertex_gather_kernel(
    const float* __restrict__ Xe, const int* __restrict__ voff,
    const int* __restrict__ velist, float* __restrict__ out)
{
    const int v = (blockIdx.x * blockDim.x + threadIdx.x) >> 6;
    const int lane = threadIdx.x & 63;
    if (v >= N_NODES) return;
    const int start = voff[v], end = voff[v + 1];

    float acc = out[(size_t)v * D + lane];   // X0
    for (int j0 = start; j0 < end; j0 += 64) {
        const int m = min(64, end - j0);
        const int ee = (lane < m) ? velist[j0 + lane] : 0;
        for (int j = 0; j < m; ++j) {
            const int e = __shfl(ee, j);
            acc += Xe[(size_t)e * D + lane];
        }
    }
    float ss = acc * acc;
    #pragma unroll
    for (int off = 1; off < 64; off <<= 1) ss += __shfl_xor(ss, off);
    const float rn = sqrtf(ss);
    const float scale = (rn == 0.f) ? 0.f : 1.f / rn;
    const float y = acc * scale;
    out[(size_t)v * D + lane] = (y > 0.f) ? y : NEG_SLOPE * y;
}

// ---------------------------------------------------------------------------
extern "C" void kernel_launch(void* const* d_in, const int* in_sizes, int n_in,
                              void* d_out, int out_size, void* d_ws, size_t ws_size,
                              hipStream_t stream)
{
    const float* X      = (const float*)d_in[0];   // (100000, 64)
    const float* degV   = (const float*)d_in[1];   // (3, 100000, 1)
    const float* Ww     = (const float*)d_in[2];   // (4, 64, 64)
    const float* Wb     = (const float*)d_in[3];   // (4, 64)
    const int*   vertex = (const int*)d_in[4];     // (1600000,)
    const int*   edges  = (const int*)d_in[5];     // (1600000,)
    float* out = (float*)d_out;                    // (100000, 64)

    // workspace layout (~21.5 MB); all int arrays padded to 16B alignment
    float* Xe    = (float*)d_ws;              // 1,920,000 f32 (7.68 MB)
    int*   ib    = (int*)(Xe + 1920000);
    int* eoff    = ib;                        // 30001 (pad to 30004)
    int* ecur    = ib + 30004;                // 30000 (pad to 30004)
    int* voff    = ib + 60008;                // 100001 (pad to 100004)
    int* vcur    = ib + 160012;               // 100000
    int* evlist  = ib + 260012;               // 1,600,000
    int* velist  = ib + 1860012;              // 1,600,000

    // zero the counter region (eoff..vcur inclusive): 260012 ints
    hipMemsetAsync(ib, 0, (size_t)260012 * sizeof(int), stream);

    x0_kernel<<<1024, 256, 0, stream>>>(X, Ww, Wb, out);

    const int pb = (N_PAIRS + 255) / 256;     // 6250
    hist_kernel<<<pb, 256, 0, stream>>>(edges,  ecur, N_PAIRS);
    hist_kernel<<<pb, 256, 0, stream>>>(vertex, vcur, N_PAIRS);

    scan_kernel<<<1, 1024, 0, stream>>>(ecur, eoff, ecur, EDGE_NUM);
    scan_kernel<<<1, 1024, 0, stream>>>(vcur, voff, vcur, N_NODES);

    fill_kernel<<<pb, 256, 0, stream>>>(edges,  vertex, ecur, evlist, N_PAIRS);
    fill_kernel<<<pb, 256, 0, stream>>>(vertex, edges,  vcur, velist, N_PAIRS);

    edge_gather_kernel<<<EDGE_NUM / 4, 256, 0, stream>>>(
        X, degV, Ww, Wb, eoff, evlist, Xe);

    vertex_gather_kernel<<<N_NODES / 4, 256, 0, stream>>>(Xe, voff, velist, out);
}

// Round 4
// 724.674 us; speedup vs baseline: 1.3049x; 1.2391x over previous
//
#include <hip/hip_runtime.h>

#define N_NODES 100000
#define N_PAIRS 1600000
#define EDGE_NUM 30000
#define D 64
#define NEG_SLOPE 0.2f
#define TN 16  // nodes staged per block in x0 gemm

// ---------------------------------------------------------------------------
// Kernel 1: X0 = X @ Ww[0]^T + Wb[0]  -> d_out (vertex gather adds onto it)
// ---------------------------------------------------------------------------
__global__ __launch_bounds__(256) void x0_kernel(
    const float* __restrict__ X, const float* __restrict__ Ww,
    const float* __restrict__ Wb, float* __restrict__ out0)
{
    __shared__ float xs[TN][D];
    const int wave = threadIdx.x >> 6;
    const int lane = threadIdx.x & 63;

    float w[64];
    const float* wrow = Ww + (size_t)lane * 64;
    #pragma unroll
    for (int i = 0; i < 64; i += 4) {
        float4 v = *(const float4*)(wrow + i);
        w[i] = v.x; w[i+1] = v.y; w[i+2] = v.z; w[i+3] = v.w;
    }
    const float b = Wb[lane];

    for (int base = blockIdx.x * TN; base < N_NODES; base += gridDim.x * TN) {
        const int ntile = min(TN, N_NODES - base);
        __syncthreads();
        {
            int n = threadIdx.x >> 4;
            int c = (threadIdx.x & 15) << 2;
            if (n < ntile)
                *(float4*)&xs[n][c] = *(const float4*)&X[(size_t)(base + n) * D + c];
        }
        __syncthreads();
        #pragma unroll
        for (int q = 0; q < 4; ++q) {
            const int n = wave * 4 + q;
            if (n < ntile) {
                float acc = 0.f;
                #pragma unroll
                for (int i = 0; i < 64; ++i) acc = fmaf(xs[n][i], w[i], acc);
                out0[(size_t)(base + n) * D + lane] = acc + b;
            }
        }
    }
}

// ---------------------------------------------------------------------------
// CSR build: fused histograms -> 2-block scan -> fused fill
// ---------------------------------------------------------------------------
__global__ __launch_bounds__(256) void hist2_kernel(
    const int* __restrict__ edges, const int* __restrict__ vertex,
    int* __restrict__ ecnt, int* __restrict__ vcnt, int n)
{
    const int i = blockIdx.x * blockDim.x + threadIdx.x;
    if (i < n) {
        atomicAdd(&ecnt[edges[i]], 1);
        atomicAdd(&vcnt[vertex[i]], 1);
    }
}

__device__ void scan_body(const int* cnt, int* off, int* cur, int n)
{
    __shared__ int wsum[16];
    __shared__ int s_carry;
    if (threadIdx.x == 0) s_carry = 0;
    __syncthreads();
    const int lane = threadIdx.x & 63;
    const int wave = threadIdx.x >> 6;

    for (int base = 0; base < n; base += 4096) {
        const int i0 = base + threadIdx.x * 4;
        int x0 = 0, x1 = 0, x2 = 0, x3 = 0;
        if (i0 + 3 < n) {
            int4 v = *(const int4*)&cnt[i0];
            x0 = v.x; x1 = v.y; x2 = v.z; x3 = v.w;
        } else {
            if (i0     < n) x0 = cnt[i0];
            if (i0 + 1 < n) x1 = cnt[i0 + 1];
            if (i0 + 2 < n) x2 = cnt[i0 + 2];
            if (i0 + 3 < n) x3 = cnt[i0 + 3];
        }
        const int tsum = x0 + x1 + x2 + x3;
        int sc = tsum;
        #pragma unroll
        for (int s = 1; s < 64; s <<= 1) {
            int y = __shfl_up(sc, s);
            if (lane >= s) sc += y;
        }
        if (lane == 63) wsum[wave] = sc;
        __syncthreads();
        int wbase = 0;
        for (int w = 0; w < wave; ++w) wbase += wsum[w];
        const int carry = s_carry;
        const int excl = carry + wbase + sc - tsum;
        const int o0 = excl, o1 = o0 + x0, o2 = o1 + x1, o3 = o2 + x2;
        if (i0 + 3 < n) {
            *(int4*)&off[i0] = make_int4(o0, o1, o2, o3);
            *(int4*)&cur[i0] = make_int4(o0, o1, o2, o3);
        } else {
            if (i0     < n) { off[i0]   = o0; cur[i0]   = o0; }
            if (i0 + 1 < n) { off[i0+1] = o1; cur[i0+1] = o1; }
            if (i0 + 2 < n) { off[i0+2] = o2; cur[i0+2] = o2; }
            if (i0 + 3 < n) { off[i0+3] = o3; cur[i0+3] = o3; }
        }
        __syncthreads();
        if (threadIdx.x == 1023) s_carry = carry + wbase + sc;
        __syncthreads();
    }
    if (threadIdx.x == 0) off[n] = s_carry;
}

__global__ __launch_bounds__(1024) void scan2_kernel(
    int* ecnt, int* eoff, int* vcnt, int* voff)
{
    if (blockIdx.x == 0) scan_body(ecnt, eoff, ecnt, EDGE_NUM);
    else                 scan_body(vcnt, voff, vcnt, N_NODES);
}

__global__ __launch_bounds__(256) void fill2_kernel(
    const int* __restrict__ edges, const int* __restrict__ vertex,
    int* __restrict__ ecur, int* __restrict__ vcur,
    int* __restrict__ evlist, int* __restrict__ velist, int n)
{
    const int i = blockIdx.x * blockDim.x + threadIdx.x;
    if (i < n) {
        const int e = edges[i];
        const int v = vertex[i];
        evlist[atomicAdd(&ecur[e], 1)] = v;
        velist[atomicAdd(&vcur[v], 1)] = e;
    }
}

// ---------------------------------------------------------------------------
// Kernel: per-edge gather. One wave per edge. Indices loaded 64-at-a-time
// per lane (vector load), broadcast via __shfl; inner loop manually unrolled
// 8-wide so 8 independent X-row gathers are in flight per wave.
// ---------------------------------------------------------------------------
__global__ __launch_bounds__(256) void edge_gather_kernel(
    const float* __restrict__ X, const float* __restrict__ degV,
    const float* __restrict__ Ww, const float* __restrict__ Wb,
    const int* __restrict__ eoff, const int* __restrict__ evlist,
    float* __restrict__ Xe)
{
    const int lane = threadIdx.x & 63;
    const int wave = threadIdx.x >> 6;
    const int e = blockIdx.x * 4 + wave;
    const int t = (e >= 10000) + (e >= 20000);   // uniform per block (bounds %4==0)

    float w[64];
    const float* wrow = Ww + ((size_t)(t + 1) * 64 + lane) * 64;
    #pragma unroll
    for (int i = 0; i < 64; i += 4) {
        float4 v = *(const float4*)(wrow + i);
        w[i] = v.x; w[i+1] = v.y; w[i+2] = v.z; w[i+3] = v.w;
    }
    const float b = Wb[(t + 1) * 64 + lane];

    const int start = eoff[e], end = eoff[e + 1];
    const float* __restrict__ degt = degV + (size_t)t * N_NODES;
    const float* __restrict__ Xl = X + lane;

    float acc0 = 0.f, acc1 = 0.f, sdeg = 0.f;
    for (int j0 = start; j0 < end; j0 += 64) {
        const int m = min(64, end - j0);
        const int vv = (lane < m) ? evlist[j0 + lane] : 0;
        int j = 0;
        for (; j + 8 <= m; j += 8) {
            int v[8];
            #pragma unroll
            for (int u = 0; u < 8; ++u) v[u] = __shfl(vv, j + u);
            float f[8], s[8];
            #pragma unroll
            for (int u = 0; u < 8; ++u) f[u] = Xl[(size_t)v[u] * D];
            #pragma unroll
            for (int u = 0; u < 8; ++u) s[u] = degt[v[u]];
            #pragma unroll
            for (int u = 0; u < 8; u += 2) {
                acc0 = fmaf(s[u],     f[u],     acc0);
                acc1 = fmaf(s[u + 1], f[u + 1], acc1);
                sdeg += s[u] + s[u + 1];
            }
        }
        for (; j < m; ++j) {
            const int v = __shfl(vv, j);
            const float s = degt[v];
            acc0 = fmaf(s, Xl[(size_t)v * D], acc0);
            sdeg += s;
        }
    }
    const float acc = acc0 + acc1;

    // r[lane] = sum_i acc_i * W[lane][i]
    float r = 0.f;
    #pragma unroll
    for (int i = 0; i < 64; ++i) r = fmaf(__shfl(acc, i), w[i], r);
    r += sdeg * b;
    const int k = max(end - start, 1);
    Xe[(size_t)e * D + lane] = r / (float)k;
}

// ---------------------------------------------------------------------------
// Kernel: per-vertex gather + X0 add + L2 normalize + leaky relu (in place)
// ---------------------------------------------------------------------------
__global__ __launch_bounds__(256) void vertex_gather_kernel(
    const float* __restrict__ Xe, const int* __restrict__ voff,
    const int* __restrict__ velist, float* __restrict__ out)
{
    const int v = blockIdx.x * 4 + (threadIdx.x >> 6);
    const int lane = threadIdx.x & 63;
    const int start = voff[v], end = voff[v + 1];
    const float* __restrict__ Xel = Xe + lane;

    float acc0 = out[(size_t)v * D + lane];   // X0
    float acc1 = 0.f;
    for (int j0 = start; j0 < end; j0 += 64) {
        const int m = min(64, end - j0);
        const int ee = (lane < m) ? velist[j0 + lane] : 0;
        int j = 0;
        for (; j + 8 <= m; j += 8) {
            int e[8];
            #pragma unroll
            for (int u = 0; u < 8; ++u) e[u] = __shfl(ee, j + u);
            float f[8];
            #pragma unroll
            for (int u = 0; u < 8; ++u) f[u] = Xel[(size_t)e[u] * D];
            #pragma unroll
            for (int u = 0; u < 8; u += 2) {
                acc0 += f[u];
                acc1 += f[u + 1];
            }
        }
        for (; j < m; ++j) {
            const int e = __shfl(ee, j);
            acc0 += Xel[(size_t)e * D];
        }
    }
    const float acc = acc0 + acc1;

    float ss = acc * acc;
    #pragma unroll
    for (int off = 1; off < 64; off <<= 1) ss += __shfl_xor(ss, off);
    const float rn = sqrtf(ss);
    const float scale = (rn == 0.f) ? 0.f : 1.f / rn;
    const float y = acc * scale;
    out[(size_t)v * D + lane] = (y > 0.f) ? y : NEG_SLOPE * y;
}

// ---------------------------------------------------------------------------
extern "C" void kernel_launch(void* const* d_in, const int* in_sizes, int n_in,
                              void* d_out, int out_size, void* d_ws, size_t ws_size,
                              hipStream_t stream)
{
    const float* X      = (const float*)d_in[0];   // (100000, 64)
    const float* degV   = (const float*)d_in[1];   // (3, 100000, 1)
    const float* Ww     = (const float*)d_in[2];   // (4, 64, 64)
    const float* Wb     = (const float*)d_in[3];   // (4, 64)
    const int*   vertex = (const int*)d_in[4];     // (1600000,)
    const int*   edges  = (const int*)d_in[5];     // (1600000,)
    float* out = (float*)d_out;                    // (100000, 64)

    // workspace layout (~21.5 MB)
    float* Xe    = (float*)d_ws;              // 1,920,000 f32 (7.68 MB)
    int*   ib    = (int*)(Xe + 1920000);
    int* eoff    = ib;                        // 30001 (pad to 30004)
    int* ecur    = ib + 30004;                // 30000 (pad to 30004)
    int* voff    = ib + 60008;                // 100001 (pad to 100004)
    int* vcur    = ib + 160012;               // 100000
    int* evlist  = ib + 260012;               // 1,600,000
    int* velist  = ib + 1860012;              // 1,600,000

    // zero the counter region (eoff..vcur inclusive)
    hipMemsetAsync(ib, 0, (size_t)260012 * sizeof(int), stream);

    x0_kernel<<<1024, 256, 0, stream>>>(X, Ww, Wb, out);

    const int pb = (N_PAIRS + 255) / 256;     // 6250
    hist2_kernel<<<pb, 256, 0, stream>>>(edges, vertex, ecur, vcur, N_PAIRS);
    scan2_kernel<<<2, 1024, 0, stream>>>(ecur, eoff, vcur, voff);
    fill2_kernel<<<pb, 256, 0, stream>>>(edges, vertex, ecur, vcur,
                                         evlist, velist, N_PAIRS);

    edge_gather_kernel<<<EDGE_NUM / 4, 256, 0, stream>>>(
        X, degV, Ww, Wb, eoff, evlist, Xe);

    vertex_gather_kernel<<<N_NODES / 4, 256, 0, stream>>>(Xe, voff, velist, out);
}

// Round 5
// 569.740 us; speedup vs baseline: 1.6597x; 1.2719x over previous
//
#include <hip/hip_runtime.h>

#define N_NODES 100000
#define N_PAIRS 1600000
#define EDGE_NUM 30000
#define D 64
#define NEG_SLOPE 0.2f
#define TN 16   // nodes staged per block in x0 gemm
#define NG 128  // pair-chunks for the XCD-pinned fill (grid = 8*NG)

// ---------------------------------------------------------------------------
// Kernel 1: X0 = X @ Ww[0]^T + Wb[0]  -> d_out (vertex gather adds onto it)
// ---------------------------------------------------------------------------
__global__ __launch_bounds__(256) void x0_kernel(
    const float* __restrict__ X, const float* __restrict__ Ww,
    const float* __restrict__ Wb, float* __restrict__ out0)
{
    __shared__ float xs[TN][D];
    const int wave = threadIdx.x >> 6;
    const int lane = threadIdx.x & 63;

    float w[64];
    const float* wrow = Ww + (size_t)lane * 64;
    #pragma unroll
    for (int i = 0; i < 64; i += 4) {
        float4 v = *(const float4*)(wrow + i);
        w[i] = v.x; w[i+1] = v.y; w[i+2] = v.z; w[i+3] = v.w;
    }
    const float b = Wb[lane];

    for (int base = blockIdx.x * TN; base < N_NODES; base += gridDim.x * TN) {
        const int ntile = min(TN, N_NODES - base);
        __syncthreads();
        {
            int n = threadIdx.x >> 4;
            int c = (threadIdx.x & 15) << 2;
            if (n < ntile)
                *(float4*)&xs[n][c] = *(const float4*)&X[(size_t)(base + n) * D + c];
        }
        __syncthreads();
        #pragma unroll
        for (int q = 0; q < 4; ++q) {
            const int n = wave * 4 + q;
            if (n < ntile) {
                float acc = 0.f;
                #pragma unroll
                for (int i = 0; i < 64; ++i) acc = fmaf(xs[n][i], w[i], acc);
                out0[(size_t)(base + n) * D + lane] = acc + b;
            }
        }
    }
}

// ---------------------------------------------------------------------------
// CSR build: fused histograms -> 2-block scan -> XCD-pinned fill
// ---------------------------------------------------------------------------
__global__ __launch_bounds__(256) void hist2_kernel(
    const int* __restrict__ edges, const int* __restrict__ vertex,
    int* __restrict__ ecnt, int* __restrict__ vcnt, int n)
{
    const int i = blockIdx.x * blockDim.x + threadIdx.x;
    if (i < n) {
        atomicAdd(&ecnt[edges[i]], 1);
        atomicAdd(&vcnt[vertex[i]], 1);
    }
}

__device__ void scan_body(const int* cnt, int* off, int* cur, int n)
{
    __shared__ int wsum[16];
    __shared__ int s_carry;
    if (threadIdx.x == 0) s_carry = 0;
    __syncthreads();
    const int lane = threadIdx.x & 63;
    const int wave = threadIdx.x >> 6;

    for (int base = 0; base < n; base += 4096) {
        const int i0 = base + threadIdx.x * 4;
        int x0 = 0, x1 = 0, x2 = 0, x3 = 0;
        if (i0 + 3 < n) {
            int4 v = *(const int4*)&cnt[i0];
            x0 = v.x; x1 = v.y; x2 = v.z; x3 = v.w;
        } else {
            if (i0     < n) x0 = cnt[i0];
            if (i0 + 1 < n) x1 = cnt[i0 + 1];
            if (i0 + 2 < n) x2 = cnt[i0 + 2];
            if (i0 + 3 < n) x3 = cnt[i0 + 3];
        }
        const int tsum = x0 + x1 + x2 + x3;
        int sc = tsum;
        #pragma unroll
        for (int s = 1; s < 64; s <<= 1) {
            int y = __shfl_up(sc, s);
            if (lane >= s) sc += y;
        }
        if (lane == 63) wsum[wave] = sc;
        __syncthreads();
        int wbase = 0;
        for (int w = 0; w < wave; ++w) wbase += wsum[w];
        const int carry = s_carry;
        const int excl = carry + wbase + sc - tsum;
        const int o0 = excl, o1 = o0 + x0, o2 = o1 + x1, o3 = o2 + x2;
        if (i0 + 3 < n) {
            *(int4*)&off[i0] = make_int4(o0, o1, o2, o3);
            *(int4*)&cur[i0] = make_int4(o0, o1, o2, o3);
        } else {
            if (i0     < n) { off[i0]   = o0; cur[i0]   = o0; }
            if (i0 + 1 < n) { off[i0+1] = o1; cur[i0+1] = o1; }
            if (i0 + 2 < n) { off[i0+2] = o2; cur[i0+2] = o2; }
            if (i0 + 3 < n) { off[i0+3] = o3; cur[i0+3] = o3; }
        }
        __syncthreads();
        if (threadIdx.x == 1023) s_carry = carry + wbase + sc;
        __syncthreads();
    }
    if (threadIdx.x == 0) off[n] = s_carry;
}

__global__ __launch_bounds__(1024) void scan2_kernel(
    int* ecnt, int* eoff, int* vcnt, int* voff)
{
    if (blockIdx.x == 0) scan_body(ecnt, eoff, ecnt, EDGE_NUM);
    else                 scan_body(vcnt, voff, vcnt, N_NODES);
}

// XCD-pinned fill: blockIdx%8 -> XCD (round-robin dispatch heuristic).
// XCD r exclusively owns edge keys [r*3750,(r+1)*3750) and vertex keys
// [r*12500,(r+1)*12500): its CSR output region (~1.6 MB) stays resident in
// its own L2 until fully written -> dense write-back instead of 16x
// random-line amplification. All 8 groups read the whole pair list (L3-served).
__global__ __launch_bounds__(256) void fill_xcd_kernel(
    const int* __restrict__ edges, const int* __restrict__ vertex,
    int* __restrict__ ecur, int* __restrict__ vcur,
    int* __restrict__ evlist, int* __restrict__ velist)
{
    const int xcd = blockIdx.x & 7;
    const int grp = blockIdx.x >> 3;               // 0..NG-1
    const int elo = xcd * (EDGE_NUM / 8);
    const int ehi = elo + (EDGE_NUM / 8);
    const int vlo = xcd * (N_NODES / 8);
    const int vhi = vlo + (N_NODES / 8);

    for (int i = grp * 256 + threadIdx.x; i < N_PAIRS; i += NG * 256) {
        const int e = edges[i];
        const int v = vertex[i];
        if (e >= elo && e < ehi) evlist[atomicAdd(&ecur[e], 1)] = v;
        if (v >= vlo && v < vhi) velist[atomicAdd(&vcur[v], 1)] = e;
    }
}

// ---------------------------------------------------------------------------
// Kernel: per-edge gather. One wave per edge. Indices loaded 64-at-a-time
// per lane (vector load), broadcast via __shfl; inner loop manually unrolled
// 8-wide so 8 independent X-row gathers are in flight per wave.
// ---------------------------------------------------------------------------
__global__ __launch_bounds__(256) void edge_gather_kernel(
    const float* __restrict__ X, const float* __restrict__ degV,
    const float* __restrict__ Ww, const float* __restrict__ Wb,
    const int* __restrict__ eoff, const int* __restrict__ evlist,
    float* __restrict__ Xe)
{
    const int lane = threadIdx.x & 63;
    const int wave = threadIdx.x >> 6;
    const int e = blockIdx.x * 4 + wave;
    const int t = (e >= 10000) + (e >= 20000);   // uniform per block (bounds %4==0)

    float w[64];
    const float* wrow = Ww + ((size_t)(t + 1) * 64 + lane) * 64;
    #pragma unroll
    for (int i = 0; i < 64; i += 4) {
        float4 v = *(const float4*)(wrow + i);
        w[i] = v.x; w[i+1] = v.y; w[i+2] = v.z; w[i+3] = v.w;
    }
    const float b = Wb[(t + 1) * 64 + lane];

    const int start = eoff[e], end = eoff[e + 1];
    const float* __restrict__ degt = degV + (size_t)t * N_NODES;
    const float* __restrict__ Xl = X + lane;

    float acc0 = 0.f, acc1 = 0.f, sdeg = 0.f;
    for (int j0 = start; j0 < end; j0 += 64) {
        const int m = min(64, end - j0);
        const int vv = (lane < m) ? evlist[j0 + lane] : 0;
        int j = 0;
        for (; j + 8 <= m; j += 8) {
            int v[8];
            #pragma unroll
            for (int u = 0; u < 8; ++u) v[u] = __shfl(vv, j + u);
            float f[8], s[8];
            #pragma unroll
            for (int u = 0; u < 8; ++u) f[u] = Xl[(size_t)v[u] * D];
            #pragma unroll
            for (int u = 0; u < 8; ++u) s[u] = degt[v[u]];
            #pragma unroll
            for (int u = 0; u < 8; u += 2) {
                acc0 = fmaf(s[u],     f[u],     acc0);
                acc1 = fmaf(s[u + 1], f[u + 1], acc1);
                sdeg += s[u] + s[u + 1];
            }
        }
        for (; j < m; ++j) {
            const int v = __shfl(vv, j);
            const float s = degt[v];
            acc0 = fmaf(s, Xl[(size_t)v * D], acc0);
            sdeg += s;
        }
    }
    const float acc = acc0 + acc1;

    // r[lane] = sum_i acc_i * W[lane][i]
    float r = 0.f;
    #pragma unroll
    for (int i = 0; i < 64; ++i) r = fmaf(__shfl(acc, i), w[i], r);
    r += sdeg * b;
    const int k = max(end - start, 1);
    Xe[(size_t)e * D + lane] = r / (float)k;
}

// ---------------------------------------------------------------------------
// Kernel: per-vertex gather + X0 add + L2 normalize + leaky relu (in place)
// ---------------------------------------------------------------------------
__global__ __launch_bounds__(256) void vertex_gather_kernel(
    const float* __restrict__ Xe, const int* __restrict__ voff,
    const int* __restrict__ velist, float* __restrict__ out)
{
    const int v = blockIdx.x * 4 + (threadIdx.x >> 6);
    const int lane = threadIdx.x & 63;
    const int start = voff[v], end = voff[v + 1];
    const float* __restrict__ Xel = Xe + lane;

    float acc0 = out[(size_t)v * D + lane];   // X0
    float acc1 = 0.f;
    for (int j0 = start; j0 < end; j0 += 64) {
        const int m = min(64, end - j0);
        const int ee = (lane < m) ? velist[j0 + lane] : 0;
        int j = 0;
        for (; j + 8 <= m; j += 8) {
            int e[8];
            #pragma unroll
            for (int u = 0; u < 8; ++u) e[u] = __shfl(ee, j + u);
            float f[8];
            #pragma unroll
            for (int u = 0; u < 8; ++u) f[u] = Xel[(size_t)e[u] * D];
            #pragma unroll
            for (int u = 0; u < 8; u += 2) {
                acc0 += f[u];
                acc1 += f[u + 1];
            }
        }
        for (; j < m; ++j) {
            const int e = __shfl(ee, j);
            acc0 += Xel[(size_t)e * D];
        }
    }
    const float acc = acc0 + acc1;

    float ss = acc * acc;
    #pragma unroll
    for (int off = 1; off < 64; off <<= 1) ss += __shfl_xor(ss, off);
    const float rn = sqrtf(ss);
    const float scale = (rn == 0.f) ? 0.f : 1.f / rn;
    const float y = acc * scale;
    out[(size_t)v * D + lane] = (y > 0.f) ? y : NEG_SLOPE * y;
}

// ---------------------------------------------------------------------------
extern "C" void kernel_launch(void* const* d_in, const int* in_sizes, int n_in,
                              void* d_out, int out_size, void* d_ws, size_t ws_size,
                              hipStream_t stream)
{
    const float* X      = (const float*)d_in[0];   // (100000, 64)
    const float* degV   = (const float*)d_in[1];   // (3, 100000, 1)
    const float* Ww     = (const float*)d_in[2];   // (4, 64, 64)
    const float* Wb     = (const float*)d_in[3];   // (4, 64)
    const int*   vertex = (const int*)d_in[4];     // (1600000,)
    const int*   edges  = (const int*)d_in[5];     // (1600000,)
    float* out = (float*)d_out;                    // (100000, 64)

    // workspace layout (~21.5 MB)
    float* Xe    = (float*)d_ws;              // 1,920,000 f32 (7.68 MB)
    int*   ib    = (int*)(Xe + 1920000);
    int* eoff    = ib;                        // 30001 (pad to 30004)
    int* ecur    = ib + 30004;                // 30000 (pad to 30004)
    int* voff    = ib + 60008;                // 100001 (pad to 100004)
    int* vcur    = ib + 160012;               // 100000
    int* evlist  = ib + 260012;               // 1,600,000
    int* velist  = ib + 1860012;              // 1,600,000

    // zero the counter region (eoff..vcur inclusive)
    hipMemsetAsync(ib, 0, (size_t)260012 * sizeof(int), stream);

    x0_kernel<<<1024, 256, 0, stream>>>(X, Ww, Wb, out);

    const int pb = (N_PAIRS + 255) / 256;     // 6250
    hist2_kernel<<<pb, 256, 0, stream>>>(edges, vertex, ecur, vcur, N_PAIRS);
    scan2_kernel<<<2, 1024, 0, stream>>>(ecur, eoff, vcur, voff);
    fill_xcd_kernel<<<8 * NG, 256, 0, stream>>>(edges, vertex, ecur, vcur,
                                                evlist, velist);

    edge_gather_kernel<<<EDGE_NUM / 4, 256, 0, stream>>>(
        X, degV, Ww, Wb, eoff, evlist, Xe);

    vertex_gather_kernel<<<N_NODES / 4, 256, 0, stream>>>(Xe, voff, velist, out);
}